// Round 11
// baseline (269.407 us; speedup 1.0000x reference)
//
#include <hip/hip_runtime.h>
#include <hip/hip_bf16.h>
#include <math.h>

#define BT 48
#define N 1024
#define F 64
#define CIN 64
#define EM 16
#define LRELU_A 0.2f
#define L2E 1.4426950408889634f
#define NBLK 768u

typedef short bf16x8 __attribute__((ext_vector_type(8)));   // 8 bf16 = 4 VGPRs
typedef float f32x4  __attribute__((ext_vector_type(4)));
typedef unsigned int u32x4 __attribute__((ext_vector_type(4)));

// exact RTNE float->bf16 bits (phase-1 only, off hot path)
__device__ __forceinline__ unsigned short f2bf(float f) {
    unsigned int u = __float_as_uint(f);
    return (unsigned short)((u + 0x7FFFu + ((u >> 16) & 1u)) >> 16);
}

// zero the grid-barrier counter each graph replay (ws is poisoned)
__global__ void k_zero(unsigned int* bar) { if (threadIdx.x == 0) *bar = 0u; }

// ------------------------------------------------------------------
// k_fused round 17: ONE dispatch = k_proj phase + grid barrier +
// k_attn phase. Evidence: six structurally different k_attn variants
// and two k_proj variants all cost ~35-40us each regardless of inner
// work (LDS/VALU/barrier/memory-path theories each falsified by a
// dedicated round). Hypothesis: fixed per-dispatch overhead dominates.
// Fusing halves the number of heavyweight dispatches; the grid
// barrier is the G16 device-scope pattern (atomicAdd + acquire spin +
// threadfence for cross-XCD visibility). Co-residency is guaranteed:
// grid=768 = 256 CU x 3 blocks (launch_bounds(256,3), 44KB LDS).
// Phase bodies are byte-equivalent to R10 (proven 117.4us).
// ------------------------------------------------------------------

#define WAIT_VM4 asm volatile("s_waitcnt vmcnt(4)" ::: "memory")
#define WAIT_VM0 asm volatile("s_waitcnt vmcnt(0)" ::: "memory")
#define BAR __builtin_amdgcn_s_barrier()

#define PAIR(x1e, x1o, x2e, x2o, bit, dest) do {                           \
    float p0_ = fmaxf((x1e) * E1, (x2e) * E2);                             \
    float p1_ = fmaxf((x1o) * E1, (x2o) * E2);                             \
    p0_ = ((mb_ >> (bit)) & 1u) ? p0_ : 0.f;                               \
    p1_ = ((mb_ >> ((bit) + 1)) & 1u) ? p1_ : 0.f;                         \
    lsum += p0_ + p1_;                                                     \
    unsigned int pk_;                                                      \
    asm("v_cvt_pk_bf16_f32 %0, %1, %2" : "=v"(pk_) : "v"(p0_), "v"(p1_)); \
    dest = pk_;                                                            \
} while (0)

#define MAKE_ONE(ch, ks, Avar, abword) do {                                \
    const int jb_ = (ch) * 128 + (ks) * 32 + q * 8;                        \
    const float4 x1a_ = *(const float4*)&sX1[jb_];                         \
    const float4 x1b_ = *(const float4*)&sX1[jb_ + 4];                     \
    const float4 x2a_ = *(const float4*)&sX2[jb_];                         \
    const float4 x2b_ = *(const float4*)&sX2[jb_ + 4];                     \
    const unsigned int mb_ = ((abword) >> (q * 8)) & 0xFFu;                \
    unsigned int u0_, u1_, u2_, u3_;                                       \
    PAIR(x1a_.x, x1a_.y, x2a_.x, x2a_.y, 0, u0_);                          \
    PAIR(x1a_.z, x1a_.w, x2a_.z, x2a_.w, 2, u1_);                          \
    PAIR(x1b_.x, x1b_.y, x2b_.x, x2b_.y, 4, u2_);                          \
    PAIR(x1b_.z, x1b_.w, x2b_.z, x2b_.w, 6, u3_);                          \
    u32x4 av_; av_.x = u0_; av_.y = u1_; av_.z = u2_; av_.w = u3_;         \
    Avar = __builtin_bit_cast(bf16x8, av_);                                \
} while (0)

#define MAKE_AFR(ch, abv, A0, A1, A2, A3) do {                             \
    MAKE_ONE(ch, 0, A0, abv.x);                                            \
    MAKE_ONE(ch, 1, A1, abv.y);                                            \
    MAKE_ONE(ch, 2, A2, abv.z);                                            \
    MAKE_ONE(ch, 3, A3, abv.w);                                            \
} while (0)

#define MFMA_KS(ct, ks, Af) do {                                           \
    const bf16x8 bb_ = *(const bf16x8*)(src_ + (ks) * 4096 +               \
                        ((ct) * 16 + m15) * 64 + slotoff);                 \
    acc##ct = __builtin_amdgcn_mfma_f32_16x16x32_bf16(Af, bb_, acc##ct,    \
                                                      0, 0, 0);            \
} while (0)

#define MFMA_CT(ct, A0, A1, A2, A3) do {                                   \
    MFMA_KS(ct, 0, A0); MFMA_KS(ct, 1, A1);                                \
    MFMA_KS(ct, 2, A2); MFMA_KS(ct, 3, A3);                                \
} while (0)

#define MFMA_CHUNK(ch, A0, A1, A2, A3) do {                                \
    const char* src_ = (const char*)(sB + ((ch) & 1) * 8192);              \
    MFMA_CT(0, A0, A1, A2, A3); MFMA_CT(1, A0, A1, A2, A3);                \
    MFMA_CT(2, A0, A1, A2, A3); MFMA_CT(3, A0, A1, A2, A3);                \
} while (0)

#define DMA(ch) do {                                                       \
    const unsigned short* dsrc_ = gBbt + (ch) * 8192 + w * 2048 + lane * 8;\
    unsigned short* ddst_ = sB + ((ch) & 1) * 8192 + w * 2048;             \
    __builtin_amdgcn_global_load_lds(                                      \
        (const __attribute__((address_space(1))) unsigned int*)(dsrc_),    \
        (__attribute__((address_space(3))) unsigned int*)(ddst_), 16, 0, 0);\
    __builtin_amdgcn_global_load_lds(                                      \
        (const __attribute__((address_space(1))) unsigned int*)(dsrc_+512),\
        (__attribute__((address_space(3))) unsigned int*)(ddst_+512), 16, 0, 0);\
    __builtin_amdgcn_global_load_lds(                                      \
        (const __attribute__((address_space(1))) unsigned int*)(dsrc_+1024),\
        (__attribute__((address_space(3))) unsigned int*)(ddst_+1024), 16, 0, 0);\
    __builtin_amdgcn_global_load_lds(                                      \
        (const __attribute__((address_space(1))) unsigned int*)(dsrc_+1536),\
        (__attribute__((address_space(3))) unsigned int*)(ddst_+1536), 16, 0, 0);\
} while (0)

#define EPI(ct, accv) do {                                                 \
    float h0_ = accv.x * rinv0, h1_ = accv.y * rinv1,                      \
          h2_ = accv.z * rinv2, h3_ = accv.w * rinv3;                      \
    h0_ = (h0_ > 0.f) ? h0_ : (__expf(h0_) - 1.f);                         \
    h1_ = (h1_ > 0.f) ? h1_ : (__expf(h1_) - 1.f);                         \
    h2_ = (h2_ > 0.f) ? h2_ : (__expf(h2_) - 1.f);                         \
    h3_ = (h3_ > 0.f) ? h3_ : (__expf(h3_) - 1.f);                         \
    float* op_ = out + (size_t)(bt2 * N + i0 + w * 16 + q * 4) * F         \
                 + (ct) * 16 + m15;                                        \
    op_[0 * F] = h0_; op_[1 * F] = h1_; op_[2 * F] = h2_; op_[3 * F] = h3_;\
} while (0)

__global__ __launch_bounds__(256, 3) void k_fused(
    const float* __restrict__ x, const float* __restrict__ W,
    const float* __restrict__ a,
    const int* __restrict__ adj,
    const float* __restrict__ emb1, const float* __restrict__ emb2,
    const float* __restrict__ a2,
    unsigned short* __restrict__ WhSw,
    float* __restrict__ s1, float* __restrict__ s2,
    unsigned int* __restrict__ adjBits,
    float* __restrict__ f1, float* __restrict__ f2,
    unsigned int* __restrict__ gbar,
    float* __restrict__ out)
{
    // 44032 B shared, re-partitioned per phase (3 blocks/CU = 132 KB)
    __shared__ __align__(16) char smem[44032];

    const int tid = threadIdx.x;
    const int b   = blockIdx.x;
    const int lane = tid & 63;
    const int w    = tid >> 6;

    // ================= PHASE 1: projection + misc =================
    {
        float* sx  = (float*)smem;                    // 64*64 f
        float* sWT = sx + 4096;                       // 64*68 f
        unsigned short* sT = (unsigned short*)(sWT + 4352);  // 64*80 s

        const int bt  = b >> 4;
        const int n0  = (b & 15) * 64;
        const size_t grow = (size_t)bt * N + n0;

        {
            const float4* xv = (const float4*)(x + grow * CIN);
            float4* sxv = (float4*)sx;
            for (int i = tid; i < 64 * CIN / 4; i += 256) sxv[i] = xv[i];
            for (int i = tid; i < CIN * F; i += 256)
                sWT[(i & 63) * 68 + (i >> 6)] = W[i];
        }
        __syncthreads();

        const int f = tid & 63;
        const float a1 = a[f], a2c = a[F + f];

        float acc[16];
#pragma unroll
        for (int t = 0; t < 16; ++t) acc[t] = 0.f;

        for (int cb = 0; cb < CIN; cb += 4) {
            const float4 wv = *(const float4*)&sWT[f * 68 + cb];
#pragma unroll
            for (int t = 0; t < 16; ++t) {
                const float4 xv = *(const float4*)&sx[(w * 16 + t) * 64 + cb];
                acc[t] = fmaf(xv.x, wv.x, acc[t]);
                acc[t] = fmaf(xv.y, wv.y, acc[t]);
                acc[t] = fmaf(xv.z, wv.z, acc[t]);
                acc[t] = fmaf(xv.w, wv.w, acc[t]);
            }
        }

#pragma unroll
        for (int t = 0; t < 16; ++t) {
            float v1 = acc[t] * a1;
            float v2 = acc[t] * a2c;
#pragma unroll
            for (int off = 32; off >= 1; off >>= 1) {
                v1 += __shfl_xor(v1, off, 64);
                v2 += __shfl_xor(v2, off, 64);
            }
            if (f == 0) {
                s1[grow + w * 16 + t] = v1;
                s2[grow + w * 16 + t] = v2;
            }
            sT[f * 80 + w * 16 + t] = f2bf(acc[t]);
        }
        __syncthreads();

        {
            const int ff = tid >> 2, qq = tid & 3;
            const int slot = (qq + ff) & 3;
            const int nb0 = (b & 15) * 2;
#pragma unroll
            for (int nbL = 0; nbL < 2; ++nbL) {
                const size_t dst = ((size_t)(bt * 32 + nb0 + nbL) * 64 + ff) * 32 + slot * 8;
                *(uint4*)&WhSw[dst] = *(const uint4*)&sT[ff * 80 + nbL * 32 + qq * 8];
            }
        }

        if (b < 128) {
            const int idx = b * 256 + tid;
            const int r = idx >> 5, w32 = idx & 31;
            const int* p = adj + (size_t)r * N + w32 * 32;
            unsigned int m = 0;
#pragma unroll
            for (int j = 0; j < 32; ++j) m |= (p[j] > 0 ? 1u : 0u) << j;
            adjBits[idx] = m;
        } else if (b < 132) {
            const int n = (b - 128) * 256 + tid;
            float v1 = 0.f, v2 = 0.f;
#pragma unroll
            for (int k = 0; k < EM; ++k) {
                v1 = fmaf(emb1[n * EM + k], a2[k], v1);
                v2 = fmaf(emb2[n * EM + k], a2[EM + k], v2);
            }
            f1[n] = v1; f2[n] = v2;
        }
    }

    // ================= GRID BARRIER (device scope) =================
    __syncthreads();
    __threadfence();                         // release phase-1 stores (agent scope)
    if (tid == 0) {
        __hip_atomic_fetch_add(gbar, 1u, __ATOMIC_ACQ_REL, __HIP_MEMORY_SCOPE_AGENT);
        while (__hip_atomic_load(gbar, __ATOMIC_ACQUIRE, __HIP_MEMORY_SCOPE_AGENT) < NBLK)
            __builtin_amdgcn_s_sleep(2);
    }
    __syncthreads();
    __threadfence();                         // acquire side (invalidate caches)

    // ================= PHASE 2: masked softmax + PV ================
    {
        float* sX1 = (float*)smem;                    // N f
        float* sX2 = sX1 + 1024;                      // N f
        unsigned short* sB = (unsigned short*)(sX2 + 1024);  // 2*8192 s
        float* sWmax = (float*)(sB + 16384);          // 4 f

        const int xcd = b & 7;                        // XCD swizzle: 6 bt/XCD
        const int idx = b >> 3;
        const int bt2 = xcd * 6 + (idx >> 4);
        const int i0  = (idx & 15) * 64;
        const int q    = lane >> 4;
        const int m15  = lane & 15;

        const int growq = i0 + w * 16 + m15;
        const uint4* abRow4 = (const uint4*)(adjBits + (size_t)growq * 32);

        const uint4 ab0 = abRow4[0], ab1 = abRow4[1], ab2 = abRow4[2], ab3 = abRow4[3];
        const uint4 ab4 = abRow4[4], ab5 = abRow4[5], ab6 = abRow4[6], ab7 = abRow4[7];
        const float rraw = s1[bt2 * N + growq] + f1[growq];

        float cmax = -1e30f;
        for (int j = tid; j < N; j += 256) {
            const float c = (s2[bt2 * N + j] + f2[j]) * L2E;
            sX1[j] = exp2f(c);
            sX2[j] = exp2f(LRELU_A * c);
            cmax = fmaxf(cmax, c);
        }
#pragma unroll
        for (int off = 32; off >= 1; off >>= 1) cmax = fmaxf(cmax, __shfl_xor(cmax, off, 64));
        if (lane == 0) sWmax[w] = cmax;
        __syncthreads();        // full drain; clean slate for vmcnt counting
        const float mx = fmaxf(fmaxf(sWmax[0], sWmax[1]), fmaxf(sWmax[2], sWmax[3]));

        const float r    = rraw * L2E;
        const float smx  = r + mx;
        const float mhat = fmaxf(smx, LRELU_A * smx);
        const float E1 = exp2f(r - mhat);
        const float E2 = exp2f(LRELU_A * r - mhat);
        float lsum = 0.f;

        const unsigned short* gBbt = WhSw + (size_t)bt2 * 65536;
        const int slotoff = ((q + m15) & 3) * 16;

        f32x4 acc0 = 0.f, acc1 = 0.f, acc2 = 0.f, acc3 = 0.f;
        bf16x8 fA0, fA1, fA2, fA3, fB0, fB1, fB2, fB3;

        MAKE_AFR(0, ab0, fA0, fA1, fA2, fA3);
        DMA(0); DMA(1);

        WAIT_VM4; BAR;
        MFMA_CHUNK(0, fA0, fA1, fA2, fA3); MAKE_AFR(1, ab1, fB0, fB1, fB2, fB3);
        BAR; DMA(2); WAIT_VM4; BAR;
        MFMA_CHUNK(1, fB0, fB1, fB2, fB3); MAKE_AFR(2, ab2, fA0, fA1, fA2, fA3);
        BAR; DMA(3); WAIT_VM4; BAR;
        MFMA_CHUNK(2, fA0, fA1, fA2, fA3); MAKE_AFR(3, ab3, fB0, fB1, fB2, fB3);
        BAR; DMA(4); WAIT_VM4; BAR;
        MFMA_CHUNK(3, fB0, fB1, fB2, fB3); MAKE_AFR(4, ab4, fA0, fA1, fA2, fA3);
        BAR; DMA(5); WAIT_VM4; BAR;
        MFMA_CHUNK(4, fA0, fA1, fA2, fA3); MAKE_AFR(5, ab5, fB0, fB1, fB2, fB3);
        BAR; DMA(6); WAIT_VM4; BAR;
        MFMA_CHUNK(5, fB0, fB1, fB2, fB3); MAKE_AFR(6, ab6, fA0, fA1, fA2, fA3);
        BAR; DMA(7); WAIT_VM4; BAR;
        MFMA_CHUNK(6, fA0, fA1, fA2, fA3); MAKE_AFR(7, ab7, fB0, fB1, fB2, fB3);
        WAIT_VM0; BAR;
        MFMA_CHUNK(7, fB0, fB1, fB2, fB3);

        lsum += __shfl_xor(lsum, 16, 64);
        lsum += __shfl_xor(lsum, 32, 64);

        const float rinv0 = 1.f / __shfl(lsum, q * 4 + 0, 64);
        const float rinv1 = 1.f / __shfl(lsum, q * 4 + 1, 64);
        const float rinv2 = 1.f / __shfl(lsum, q * 4 + 2, 64);
        const float rinv3 = 1.f / __shfl(lsum, q * 4 + 3, 64);

        EPI(0, acc0); EPI(1, acc1); EPI(2, acc2); EPI(3, acc3);
    }
}

// ------------------------------------------------------------------
extern "C" void kernel_launch(void* const* d_in, const int* in_sizes, int n_in,
                              void* d_out, int out_size, void* d_ws, size_t ws_size,
                              hipStream_t stream)
{
    const float* x    = (const float*)d_in[0];
    const int*   adj  = (const int*)  d_in[1];
    const float* emb1 = (const float*)d_in[2];
    const float* emb2 = (const float*)d_in[3];
    const float* W    = (const float*)d_in[4];
    const float* a    = (const float*)d_in[5];
    const float* a2   = (const float*)d_in[6];
    float* out = (float*)d_out;

    unsigned short* WhSw = (unsigned short*)d_ws;             // 6.29 MB
    float* s1 = (float*)(WhSw + (size_t)BT * 65536);
    float* s2 = s1 + BT * N;
    float* f1 = s2 + BT * N;
    float* f2 = f1 + N;
    unsigned int* adjBits = (unsigned int*)(f2 + N);          // 128 KB
    unsigned int* gbar = adjBits + 32768;                     // 4 B barrier ctr

    hipLaunchKernelGGL(k_zero, dim3(1), dim3(64), 0, stream, gbar);
    hipLaunchKernelGGL(k_fused, dim3(NBLK), dim3(256), 0, stream,
                       x, W, a, adj, emb1, emb2, a2, WhSw, s1, s2,
                       adjBits, f1, f2, gbar, out);
}

// Round 12
// 121.957 us; speedup vs baseline: 2.2090x; 2.2090x over previous
//
#include <hip/hip_runtime.h>
#include <hip/hip_bf16.h>
#include <math.h>

#define BT 48
#define N 1024
#define F 64
#define CIN 64
#define EM 16
#define LRELU_A 0.2f
#define L2E 1.4426950408889634f

typedef short bf16x8 __attribute__((ext_vector_type(8)));   // 8 bf16 = 4 VGPRs
typedef float f32x4  __attribute__((ext_vector_type(4)));
typedef unsigned int u32x4 __attribute__((ext_vector_type(4)));

// exact RTNE float->bf16 bits (k_proj only, off hot path)
__device__ __forceinline__ unsigned short f2bf(float f) {
    unsigned int u = __float_as_uint(f);
    return (unsigned short)((u + 0x7FFFu + ((u >> 16) & 1u)) >> 16);
}

// ------------------------------------------------------------------
// k_proj_misc (R10-exact, unchanged for attribution)
// ------------------------------------------------------------------
__global__ __launch_bounds__(256) void k_proj_misc(
    const float* __restrict__ x, const float* __restrict__ W,
    const float* __restrict__ a,
    const int* __restrict__ adj,
    const float* __restrict__ emb1, const float* __restrict__ emb2,
    const float* __restrict__ a2,
    unsigned short* __restrict__ WhSw,
    float* __restrict__ s1, float* __restrict__ s2,
    unsigned int* __restrict__ adjBits,
    float* __restrict__ f1, float* __restrict__ f2)
{
    const int tid = threadIdx.x;
    const int b   = blockIdx.x;

    __shared__ __align__(16) float sx[64 * 64];
    __shared__ __align__(16) float sWT[64 * 68];
    __shared__ __align__(16) unsigned short sT[64 * 80];

    const int bt  = b >> 4;
    const int n0  = (b & 15) * 64;
    const size_t grow = (size_t)bt * N + n0;

    {
        const float4* xv = (const float4*)(x + grow * CIN);
        float4* sxv = (float4*)sx;
        for (int i = tid; i < 64 * CIN / 4; i += 256) sxv[i] = xv[i];
        for (int i = tid; i < CIN * F; i += 256)
            sWT[(i & 63) * 68 + (i >> 6)] = W[i];
    }
    __syncthreads();

    const int f = tid & 63;
    const int w = tid >> 6;
    const float a1 = a[f], a2c = a[F + f];

    float acc[16];
#pragma unroll
    for (int t = 0; t < 16; ++t) acc[t] = 0.f;

    for (int cb = 0; cb < CIN; cb += 4) {
        const float4 wv = *(const float4*)&sWT[f * 68 + cb];
#pragma unroll
        for (int t = 0; t < 16; ++t) {
            const float4 xv = *(const float4*)&sx[(w * 16 + t) * 64 + cb];
            acc[t] = fmaf(xv.x, wv.x, acc[t]);
            acc[t] = fmaf(xv.y, wv.y, acc[t]);
            acc[t] = fmaf(xv.z, wv.z, acc[t]);
            acc[t] = fmaf(xv.w, wv.w, acc[t]);
        }
    }

#pragma unroll
    for (int t = 0; t < 16; ++t) {
        float v1 = acc[t] * a1;
        float v2 = acc[t] * a2c;
#pragma unroll
        for (int off = 32; off >= 1; off >>= 1) {
            v1 += __shfl_xor(v1, off, 64);
            v2 += __shfl_xor(v2, off, 64);
        }
        if (f == 0) {
            s1[grow + w * 16 + t] = v1;
            s2[grow + w * 16 + t] = v2;
        }
        sT[f * 80 + w * 16 + t] = f2bf(acc[t]);
    }
    __syncthreads();

    {
        const int ff = tid >> 2, qq = tid & 3;
        const int slot = (qq + ff) & 3;
        const int nb0 = (b & 15) * 2;
#pragma unroll
        for (int nbL = 0; nbL < 2; ++nbL) {
            const size_t dst = ((size_t)(bt * 32 + nb0 + nbL) * 64 + ff) * 32 + slot * 8;
            *(uint4*)&WhSw[dst] = *(const uint4*)&sT[ff * 80 + nbL * 32 + qq * 8];
        }
    }

    if (b < 128) {
        const int idx = b * 256 + tid;
        const int r = idx >> 5, w32 = idx & 31;
        const int* p = adj + (size_t)r * N + w32 * 32;
        unsigned int m = 0;
#pragma unroll
        for (int j = 0; j < 32; ++j) m |= (p[j] > 0 ? 1u : 0u) << j;
        adjBits[idx] = m;
    } else if (b < 132) {
        const int n = (b - 128) * 256 + tid;
        float v1 = 0.f, v2 = 0.f;
#pragma unroll
        for (int k = 0; k < EM; ++k) {
            v1 = fmaf(emb1[n * EM + k], a2[k], v1);
            v2 = fmaf(emb2[n * EM + k], a2[EM + k], v2);
        }
        f1[n] = v1; f2[n] = v2;
    }
}

// ------------------------------------------------------------------
// k_attn round 18 "tlp32": grid-capped-occupancy fix. Evidence:
// VALUBusy(29%) == modeled issue time at 3 waves/SIMD; ~70% of time
// ALL resident waves stalled on memory (grid=768 == exactly 3
// blocks/CU; HW would allow far more). Fix: 1536 blocks x 32 rows.
// Wave w: row-tile rt=w&1 (16 rows), k-half kh=w>>1 (4 chunks).
// B direct from global (L2-resident; chip-total loads/traffic equal
// to R6). LDS 16.5KB, launch_bounds(256,6) -> 6 blocks/CU = 24
// waves/CU (2x TLP). Cross-wave k-reduction: upper waves dump
// acc+lsum to LDS, one barrier, lower waves merge + epilogue.
// Chip-total PAIR/MFMA work unchanged; staging exps 2x (+~2.5us).
// ------------------------------------------------------------------

#define PAIR(x1e, x1o, x2e, x2o, bit, dest) do {                           \
    float p0_ = fmaxf((x1e) * E1, (x2e) * E2);                             \
    float p1_ = fmaxf((x1o) * E1, (x2o) * E2);                             \
    p0_ = ((mb_ >> (bit)) & 1u) ? p0_ : 0.f;                               \
    p1_ = ((mb_ >> ((bit) + 1)) & 1u) ? p1_ : 0.f;                         \
    lsum += p0_ + p1_;                                                     \
    unsigned int pk_;                                                      \
    asm("v_cvt_pk_bf16_f32 %0, %1, %2" : "=v"(pk_) : "v"(p0_), "v"(p1_)); \
    dest = pk_;                                                            \
} while (0)

#define MAKE_ONE(ch, ks, Avar, abword) do {                                \
    const int jb_ = (ch) * 128 + (ks) * 32 + q * 8;                        \
    const float4 x1a_ = *(const float4*)&sX1[jb_];                         \
    const float4 x1b_ = *(const float4*)&sX1[jb_ + 4];                     \
    const float4 x2a_ = *(const float4*)&sX2[jb_];                         \
    const float4 x2b_ = *(const float4*)&sX2[jb_ + 4];                     \
    const unsigned int mb_ = ((abword) >> (q * 8)) & 0xFFu;                \
    unsigned int u0_, u1_, u2_, u3_;                                       \
    PAIR(x1a_.x, x1a_.y, x2a_.x, x2a_.y, 0, u0_);                          \
    PAIR(x1a_.z, x1a_.w, x2a_.z, x2a_.w, 2, u1_);                          \
    PAIR(x1b_.x, x1b_.y, x2b_.x, x2b_.y, 4, u2_);                          \
    PAIR(x1b_.z, x1b_.w, x2b_.z, x2b_.w, 6, u3_);                          \
    u32x4 av_; av_.x = u0_; av_.y = u1_; av_.z = u2_; av_.w = u3_;         \
    Avar = __builtin_bit_cast(bf16x8, av_);                                \
} while (0)

// B-fragment straight from global (WhSw), slot-swizzled
#define MFMA_G(ct, ks, Af) do {                                            \
    const bf16x8 bb_ = *(const bf16x8*)(gBc + (size_t)ch_ * 16384 +        \
                        (ks) * 4096 + ((ct) * 16 + m15) * 64 + slotoff);   \
    acc##ct = __builtin_amdgcn_mfma_f32_16x16x32_bf16(Af, bb_, acc##ct,    \
                                                      0, 0, 0);            \
} while (0)

#define CHUNKG(ch) do { const int ch_ = (ch);                              \
    const uint4 abv_ = *(const uint4*)(abRow + ch_ * 4);                   \
    MAKE_ONE(ch_, 0, fA0, abv_.x);                                         \
    MAKE_ONE(ch_, 1, fA1, abv_.y);                                         \
    MAKE_ONE(ch_, 2, fA2, abv_.z);                                         \
    MAKE_ONE(ch_, 3, fA3, abv_.w);                                         \
    MFMA_G(0, 0, fA0); MFMA_G(0, 1, fA1); MFMA_G(0, 2, fA2); MFMA_G(0, 3, fA3); \
    MFMA_G(1, 0, fA0); MFMA_G(1, 1, fA1); MFMA_G(1, 2, fA2); MFMA_G(1, 3, fA3); \
    MFMA_G(2, 0, fA0); MFMA_G(2, 1, fA1); MFMA_G(2, 2, fA2); MFMA_G(2, 3, fA3); \
    MFMA_G(3, 0, fA0); MFMA_G(3, 1, fA1); MFMA_G(3, 2, fA2); MFMA_G(3, 3, fA3); \
} while (0)

#define EPI(ct, accv) do {                                                 \
    float h0_ = accv.x * rinv0, h1_ = accv.y * rinv1,                      \
          h2_ = accv.z * rinv2, h3_ = accv.w * rinv3;                      \
    h0_ = (h0_ > 0.f) ? h0_ : (__expf(h0_) - 1.f);                         \
    h1_ = (h1_ > 0.f) ? h1_ : (__expf(h1_) - 1.f);                         \
    h2_ = (h2_ > 0.f) ? h2_ : (__expf(h2_) - 1.f);                         \
    h3_ = (h3_ > 0.f) ? h3_ : (__expf(h3_) - 1.f);                         \
    float* op_ = out + (size_t)(bt * N + i0 + rt * 16 + q * 4) * F         \
                 + (ct) * 16 + m15;                                        \
    op_[0 * F] = h0_; op_[1 * F] = h1_; op_[2 * F] = h2_; op_[3 * F] = h3_;\
} while (0)

__global__ __launch_bounds__(256, 6) void k_attn(
    const unsigned int* __restrict__ adjBits,
    const unsigned short* __restrict__ WhSw,
    const float* __restrict__ s1, const float* __restrict__ s2,
    const float* __restrict__ f1v, const float* __restrict__ f2v,
    float* __restrict__ out)
{
    __shared__ __align__(16) float sX1[N];                  // 2^c   (scaled domain)
    __shared__ __align__(16) float sX2[N];                  // 2^.2c
    __shared__ __align__(16) float sP[2048];                // 8 KB k-partials
    __shared__ float sLs[2][16];
    __shared__ float sWmax[4];

    const int tid  = threadIdx.x;
    const int xcd = blockIdx.x & 7;                         // 192 idx/XCD
    const int idx = blockIdx.x >> 3;
    const int bt  = xcd * 6 + (idx >> 5);                   // 6 bt per XCD
    const int i0  = (idx & 31) * 32;                        // 32-row slice
    const int lane = tid & 63;
    const int w    = tid >> 6;
    const int q    = lane >> 4;
    const int m15  = lane & 15;
    const int rt   = w & 1;                                 // row-tile (16 rows)
    const int kh4  = (w >> 1) * 4;                          // chunk base (k-half)

    const int growq = i0 + rt * 16 + m15;
    const unsigned int* abRow = adjBits + (size_t)growq * 32;
    const float rraw = s1[bt * N + growq] + f1v[growq];

    // stage X1/X2 and track block max of c (scaled by log2e)
    float cmax = -1e30f;
    for (int j = tid; j < N; j += 256) {
        const float c = (s2[bt * N + j] + f2v[j]) * L2E;
        sX1[j] = exp2f(c);
        sX2[j] = exp2f(LRELU_A * c);
        cmax = fmaxf(cmax, c);
    }
#pragma unroll
    for (int off = 32; off >= 1; off >>= 1) cmax = fmaxf(cmax, __shfl_xor(cmax, off, 64));
    if (lane == 0) sWmax[w] = cmax;
    __syncthreads();
    const float mx = fmaxf(fmaxf(sWmax[0], sWmax[1]), fmaxf(sWmax[2], sWmax[3]));

    const float r    = rraw * L2E;                          // scaled domain
    const float smx  = r + mx;
    const float mhat = fmaxf(smx, LRELU_A * smx);           // >= every scaled e in row
    const float E1 = exp2f(r - mhat);
    const float E2 = exp2f(LRELU_A * r - mhat);
    float lsum = 0.f;

    const char* gBc = (const char*)(WhSw + (size_t)bt * 65536);
    const int slotoff = ((q + m15) & 3) * 16;               // XOR-swizzled slot

    f32x4 acc0 = 0.f, acc1 = 0.f, acc2 = 0.f, acc3 = 0.f;
    bf16x8 fA0, fA1, fA2, fA3;

    // this wave's 4 chunks (its k-half), barrier-free
    CHUNKG(kh4 + 0);
    CHUNKG(kh4 + 1);
    CHUNKG(kh4 + 2);
    CHUNKG(kh4 + 3);

    // within-wave q-reduction: every lane -> full row sum for row m15
    lsum += __shfl_xor(lsum, 16, 64);
    lsum += __shfl_xor(lsum, 32, 64);

    // cross-wave k-half reduction: waves 2,3 dump; waves 0,1 merge
    if (w >= 2) {
        *(f32x4*)&sP[(rt * 4 + 0) * 256 + lane * 4] = acc0;
        *(f32x4*)&sP[(rt * 4 + 1) * 256 + lane * 4] = acc1;
        *(f32x4*)&sP[(rt * 4 + 2) * 256 + lane * 4] = acc2;
        *(f32x4*)&sP[(rt * 4 + 3) * 256 + lane * 4] = acc3;
        if (q == 0) sLs[rt][m15] = lsum;
    }
    __syncthreads();

    if (w < 2) {
        acc0 += *(const f32x4*)&sP[(rt * 4 + 0) * 256 + lane * 4];
        acc1 += *(const f32x4*)&sP[(rt * 4 + 1) * 256 + lane * 4];
        acc2 += *(const f32x4*)&sP[(rt * 4 + 2) * 256 + lane * 4];
        acc3 += *(const f32x4*)&sP[(rt * 4 + 3) * 256 + lane * 4];
        const float ltot = lsum + sLs[rt][m15];

        const float rinv0 = 1.f / __shfl(ltot, q * 4 + 0, 64);
        const float rinv1 = 1.f / __shfl(ltot, q * 4 + 1, 64);
        const float rinv2 = 1.f / __shfl(ltot, q * 4 + 2, 64);
        const float rinv3 = 1.f / __shfl(ltot, q * 4 + 3, 64);

        EPI(0, acc0); EPI(1, acc1); EPI(2, acc2); EPI(3, acc3);
    }
}

// ------------------------------------------------------------------
extern "C" void kernel_launch(void* const* d_in, const int* in_sizes, int n_in,
                              void* d_out, int out_size, void* d_ws, size_t ws_size,
                              hipStream_t stream)
{
    const float* x    = (const float*)d_in[0];
    const int*   adj  = (const int*)  d_in[1];
    const float* emb1 = (const float*)d_in[2];
    const float* emb2 = (const float*)d_in[3];
    const float* W    = (const float*)d_in[4];
    const float* a    = (const float*)d_in[5];
    const float* a2   = (const float*)d_in[6];
    float* out = (float*)d_out;

    unsigned short* WhSw = (unsigned short*)d_ws;             // 6.29 MB
    float* s1 = (float*)(WhSw + (size_t)BT * 65536);
    float* s2 = s1 + BT * N;
    float* f1 = s2 + BT * N;
    float* f2 = f1 + N;
    unsigned int* adjBits = (unsigned int*)(f2 + N);          // 128 KB

    hipLaunchKernelGGL(k_proj_misc, dim3(768), dim3(256), 0, stream,
                       x, W, a, adj, emb1, emb2, a2, WhSw, s1, s2, adjBits, f1, f2);
    hipLaunchKernelGGL(k_attn, dim3(BT * 32), dim3(256), 0, stream,
                       adjBits, WhSw, s1, s2, f1, f2, out);
}

// Round 13
// 116.461 us; speedup vs baseline: 2.3133x; 1.0472x over previous
//
#include <hip/hip_runtime.h>
#include <hip/hip_bf16.h>
#include <math.h>

#define BT 48
#define N 1024
#define F 64
#define CIN 64
#define EM 16
#define LRELU_A 0.2f
#define L2E 1.4426950408889634f

typedef short bf16x8 __attribute__((ext_vector_type(8)));   // 8 bf16 = 4 VGPRs
typedef float f32x4  __attribute__((ext_vector_type(4)));
typedef unsigned int u32x4 __attribute__((ext_vector_type(4)));

// exact RTNE float->bf16 bits (k_proj only, off hot path)
__device__ __forceinline__ unsigned short f2bf(float f) {
    unsigned int u = __float_as_uint(f);
    return (unsigned short)((u + 0x7FFFu + ((u >> 16) & 1u)) >> 16);
}

// ------------------------------------------------------------------
// k_proj_misc (R10-exact, unchanged for attribution)
// ------------------------------------------------------------------
__global__ __launch_bounds__(256) void k_proj_misc(
    const float* __restrict__ x, const float* __restrict__ W,
    const float* __restrict__ a,
    const int* __restrict__ adj,
    const float* __restrict__ emb1, const float* __restrict__ emb2,
    const float* __restrict__ a2,
    unsigned short* __restrict__ WhSw,
    float* __restrict__ s1, float* __restrict__ s2,
    unsigned int* __restrict__ adjBits,
    float* __restrict__ f1, float* __restrict__ f2)
{
    const int tid = threadIdx.x;
    const int b   = blockIdx.x;

    __shared__ __align__(16) float sx[64 * 64];
    __shared__ __align__(16) float sWT[64 * 68];
    __shared__ __align__(16) unsigned short sT[64 * 80];

    const int bt  = b >> 4;
    const int n0  = (b & 15) * 64;
    const size_t grow = (size_t)bt * N + n0;

    {
        const float4* xv = (const float4*)(x + grow * CIN);
        float4* sxv = (float4*)sx;
        for (int i = tid; i < 64 * CIN / 4; i += 256) sxv[i] = xv[i];
        for (int i = tid; i < CIN * F; i += 256)
            sWT[(i & 63) * 68 + (i >> 6)] = W[i];
    }
    __syncthreads();

    const int f = tid & 63;
    const int w = tid >> 6;
    const float a1 = a[f], a2c = a[F + f];

    float acc[16];
#pragma unroll
    for (int t = 0; t < 16; ++t) acc[t] = 0.f;

    for (int cb = 0; cb < CIN; cb += 4) {
        const float4 wv = *(const float4*)&sWT[f * 68 + cb];
#pragma unroll
        for (int t = 0; t < 16; ++t) {
            const float4 xv = *(const float4*)&sx[(w * 16 + t) * 64 + cb];
            acc[t] = fmaf(xv.x, wv.x, acc[t]);
            acc[t] = fmaf(xv.y, wv.y, acc[t]);
            acc[t] = fmaf(xv.z, wv.z, acc[t]);
            acc[t] = fmaf(xv.w, wv.w, acc[t]);
        }
    }

#pragma unroll
    for (int t = 0; t < 16; ++t) {
        float v1 = acc[t] * a1;
        float v2 = acc[t] * a2c;
#pragma unroll
        for (int off = 32; off >= 1; off >>= 1) {
            v1 += __shfl_xor(v1, off, 64);
            v2 += __shfl_xor(v2, off, 64);
        }
        if (f == 0) {
            s1[grow + w * 16 + t] = v1;
            s2[grow + w * 16 + t] = v2;
        }
        sT[f * 80 + w * 16 + t] = f2bf(acc[t]);
    }
    __syncthreads();

    {
        const int ff = tid >> 2, qq = tid & 3;
        const int slot = (qq + ff) & 3;
        const int nb0 = (b & 15) * 2;
#pragma unroll
        for (int nbL = 0; nbL < 2; ++nbL) {
            const size_t dst = ((size_t)(bt * 32 + nb0 + nbL) * 64 + ff) * 32 + slot * 8;
            *(uint4*)&WhSw[dst] = *(const uint4*)&sT[ff * 80 + nbL * 32 + qq * 8];
        }
    }

    if (b < 128) {
        const int idx = b * 256 + tid;
        const int r = idx >> 5, w32 = idx & 31;
        const int* p = adj + (size_t)r * N + w32 * 32;
        unsigned int m = 0;
#pragma unroll
        for (int j = 0; j < 32; ++j) m |= (p[j] > 0 ? 1u : 0u) << j;
        adjBits[idx] = m;
    } else if (b < 132) {
        const int n = (b - 128) * 256 + tid;
        float v1 = 0.f, v2 = 0.f;
#pragma unroll
        for (int k = 0; k < EM; ++k) {
            v1 = fmaf(emb1[n * EM + k], a2[k], v1);
            v2 = fmaf(emb2[n * EM + k], a2[EM + k], v2);
        }
        f1[n] = v1; f2[n] = v2;
    }
}

// ------------------------------------------------------------------
// k_attn round 19 "regB-pp": named-register ping-pong prefetch of B
// from GLOBAL (L2/L3-resident). Mechanism being fixed: R6's regB had
// VGPR=44 -> ~2.5 loads in flight -> 128 x ~400cyc / 2.5 = 26k
// exposed stall cyc/wave (matches counters exactly). Here each
// 8-fragment load batch (32 VGPR bank) is issued >= 400 cycles of
// independent VALU (MAKE_AFR) + MFMA before its first use:
//   [P preloaded] -> issue Q(ch,ct23) -> MAKE_AFR(ch) -> MFMA P
//   -> issue P(ch+1,ct01) -> MFMA Q -> next chunk
// No DMA, no loop barriers, LDS = sX only (8.7KB). 3 blocks/CU.
// ------------------------------------------------------------------

#define PAIR(x1e, x1o, x2e, x2o, bit, dest) do {                           \
    float p0_ = fmaxf((x1e) * E1, (x2e) * E2);                             \
    float p1_ = fmaxf((x1o) * E1, (x2o) * E2);                             \
    p0_ = ((mb_ >> (bit)) & 1u) ? p0_ : 0.f;                               \
    p1_ = ((mb_ >> ((bit) + 1)) & 1u) ? p1_ : 0.f;                         \
    lsum += p0_ + p1_;                                                     \
    unsigned int pk_;                                                      \
    asm("v_cvt_pk_bf16_f32 %0, %1, %2" : "=v"(pk_) : "v"(p0_), "v"(p1_)); \
    dest = pk_;                                                            \
} while (0)

#define MAKE_ONE(ch, ks, Avar, abword) do {                                \
    const int jb_ = (ch) * 128 + (ks) * 32 + q * 8;                        \
    const float4 x1a_ = *(const float4*)&sX1[jb_];                         \
    const float4 x1b_ = *(const float4*)&sX1[jb_ + 4];                     \
    const float4 x2a_ = *(const float4*)&sX2[jb_];                         \
    const float4 x2b_ = *(const float4*)&sX2[jb_ + 4];                     \
    const unsigned int mb_ = ((abword) >> (q * 8)) & 0xFFu;                \
    unsigned int u0_, u1_, u2_, u3_;                                       \
    PAIR(x1a_.x, x1a_.y, x2a_.x, x2a_.y, 0, u0_);                          \
    PAIR(x1a_.z, x1a_.w, x2a_.z, x2a_.w, 2, u1_);                          \
    PAIR(x1b_.x, x1b_.y, x2b_.x, x2b_.y, 4, u2_);                          \
    PAIR(x1b_.z, x1b_.w, x2b_.z, x2b_.w, 6, u3_);                          \
    u32x4 av_; av_.x = u0_; av_.y = u1_; av_.z = u2_; av_.w = u3_;         \
    Avar = __builtin_bit_cast(bf16x8, av_);                                \
} while (0)

#define MAKE_AFR(ch, abv, A0, A1, A2, A3) do {                             \
    MAKE_ONE(ch, 0, A0, abv.x);                                            \
    MAKE_ONE(ch, 1, A1, abv.y);                                            \
    MAKE_ONE(ch, 2, A2, abv.z);                                            \
    MAKE_ONE(ch, 3, A3, abv.w);                                            \
} while (0)

// one B-fragment from global WhSw (slot-swizzled layout)
#define LB(v, ch, ks, ct)                                                  \
    v = *(const bf16x8*)(gBc + (size_t)(ch) * 16384 + (ks) * 4096 +        \
        ((ct) * 16 + m15) * 64 + slotoff)

// 8-fragment bank: ks=0..3 for two ct columns
#define LOAD8(B0, B1, B2, B3, B4, B5, B6, B7, ch, ct0, ct1) do {           \
    LB(B0, ch, 0, ct0); LB(B1, ch, 1, ct0);                                \
    LB(B2, ch, 2, ct0); LB(B3, ch, 3, ct0);                                \
    LB(B4, ch, 0, ct1); LB(B5, ch, 1, ct1);                                \
    LB(B6, ch, 2, ct1); LB(B7, ch, 3, ct1);                                \
} while (0)

#define MFMA8(B0, B1, B2, B3, B4, B5, B6, B7, c0, c1) do {                 \
    acc##c0 = __builtin_amdgcn_mfma_f32_16x16x32_bf16(fA0, B0, acc##c0, 0, 0, 0); \
    acc##c0 = __builtin_amdgcn_mfma_f32_16x16x32_bf16(fA1, B1, acc##c0, 0, 0, 0); \
    acc##c0 = __builtin_amdgcn_mfma_f32_16x16x32_bf16(fA2, B2, acc##c0, 0, 0, 0); \
    acc##c0 = __builtin_amdgcn_mfma_f32_16x16x32_bf16(fA3, B3, acc##c0, 0, 0, 0); \
    acc##c1 = __builtin_amdgcn_mfma_f32_16x16x32_bf16(fA0, B4, acc##c1, 0, 0, 0); \
    acc##c1 = __builtin_amdgcn_mfma_f32_16x16x32_bf16(fA1, B5, acc##c1, 0, 0, 0); \
    acc##c1 = __builtin_amdgcn_mfma_f32_16x16x32_bf16(fA2, B6, acc##c1, 0, 0, 0); \
    acc##c1 = __builtin_amdgcn_mfma_f32_16x16x32_bf16(fA3, B7, acc##c1, 0, 0, 0); \
} while (0)

// mid-pipeline chunk: Q-bank load covered by MAKE_AFR; P-reload for
// ch+1 covered by MFMA(Q) + next chunk's MAKE_AFR
#define CHUNK_MID(ch) do {                                                 \
    LOAD8(Q0, Q1, Q2, Q3, Q4, Q5, Q6, Q7, ch, 2, 3);                       \
    const uint4 abv_ = abRow4[ch];                                         \
    MAKE_AFR(ch, abv_, fA0, fA1, fA2, fA3);                                \
    MFMA8(P0, P1, P2, P3, P4, P5, P6, P7, 0, 1);                           \
    LOAD8(P0, P1, P2, P3, P4, P5, P6, P7, (ch) + 1, 0, 1);                 \
    MFMA8(Q0, Q1, Q2, Q3, Q4, Q5, Q6, Q7, 2, 3);                           \
} while (0)

#define CHUNK_LAST(ch) do {                                                \
    LOAD8(Q0, Q1, Q2, Q3, Q4, Q5, Q6, Q7, ch, 2, 3);                       \
    const uint4 abv_ = abRow4[ch];                                         \
    MAKE_AFR(ch, abv_, fA0, fA1, fA2, fA3);                                \
    MFMA8(P0, P1, P2, P3, P4, P5, P6, P7, 0, 1);                           \
    MFMA8(Q0, Q1, Q2, Q3, Q4, Q5, Q6, Q7, 2, 3);                           \
} while (0)

#define EPI(ct, accv) do {                                                 \
    float h0_ = accv.x * rinv0, h1_ = accv.y * rinv1,                      \
          h2_ = accv.z * rinv2, h3_ = accv.w * rinv3;                      \
    h0_ = (h0_ > 0.f) ? h0_ : (__expf(h0_) - 1.f);                         \
    h1_ = (h1_ > 0.f) ? h1_ : (__expf(h1_) - 1.f);                         \
    h2_ = (h2_ > 0.f) ? h2_ : (__expf(h2_) - 1.f);                         \
    h3_ = (h3_ > 0.f) ? h3_ : (__expf(h3_) - 1.f);                         \
    float* op_ = out + (size_t)(bt * N + i0 + w * 16 + q * 4) * F          \
                 + (ct) * 16 + m15;                                        \
    op_[0 * F] = h0_; op_[1 * F] = h1_; op_[2 * F] = h2_; op_[3 * F] = h3_;\
} while (0)

__global__ __launch_bounds__(256, 3) void k_attn(
    const unsigned int* __restrict__ adjBits,
    const unsigned short* __restrict__ WhSw,
    const float* __restrict__ s1, const float* __restrict__ s2,
    const float* __restrict__ f1v, const float* __restrict__ f2v,
    float* __restrict__ out)
{
    __shared__ __align__(16) float sX1[N];                  // 2^c   (scaled domain)
    __shared__ __align__(16) float sX2[N];                  // 2^.2c
    __shared__ float sWmax[4];

    const int tid  = threadIdx.x;
    const int xcd = blockIdx.x & 7;                         // XCD swizzle: 6 bt/XCD
    const int idx = blockIdx.x >> 3;
    const int bt  = xcd * 6 + (idx >> 4);
    const int i0  = (idx & 15) * 64;
    const int lane = tid & 63;
    const int w    = tid >> 6;
    const int q    = lane >> 4;
    const int m15  = lane & 15;

    const int growq = i0 + w * 16 + m15;
    const uint4* abRow4 = (const uint4*)(adjBits + (size_t)growq * 32);
    const float rraw = s1[bt * N + growq] + f1v[growq];

    // stage X1/X2 and track block max of c (scaled by log2e)
    float cmax = -1e30f;
    for (int j = tid; j < N; j += 256) {
        const float c = (s2[bt * N + j] + f2v[j]) * L2E;
        sX1[j] = exp2f(c);
        sX2[j] = exp2f(LRELU_A * c);
        cmax = fmaxf(cmax, c);
    }
#pragma unroll
    for (int off = 32; off >= 1; off >>= 1) cmax = fmaxf(cmax, __shfl_xor(cmax, off, 64));
    if (lane == 0) sWmax[w] = cmax;
    __syncthreads();
    const float mx = fmaxf(fmaxf(sWmax[0], sWmax[1]), fmaxf(sWmax[2], sWmax[3]));

    const float r    = rraw * L2E;                          // scaled domain
    const float smx  = r + mx;
    const float mhat = fmaxf(smx, LRELU_A * smx);           // >= every scaled e in row
    const float E1 = exp2f(r - mhat);
    const float E2 = exp2f(LRELU_A * r - mhat);
    float lsum = 0.f;

    const char* gBc = (const char*)(WhSw + (size_t)bt * 65536);
    const int slotoff = ((q + m15) & 3) * 16;               // XOR-swizzled slot

    f32x4 acc0 = 0.f, acc1 = 0.f, acc2 = 0.f, acc3 = 0.f;
    bf16x8 fA0, fA1, fA2, fA3;
    bf16x8 P0, P1, P2, P3, P4, P5, P6, P7;                  // bank P (32 VGPR)
    bf16x8 Q0, Q1, Q2, Q3, Q4, Q5, Q6, Q7;                  // bank Q (32 VGPR)

    // prologue: preload P(ch0, ct01); its latency hides under nothing
    // but the first MAKE_AFR covers it before first use anyway.
    LOAD8(P0, P1, P2, P3, P4, P5, P6, P7, 0, 0, 1);

    CHUNK_MID(0); CHUNK_MID(1); CHUNK_MID(2); CHUNK_MID(3);
    CHUNK_MID(4); CHUNK_MID(5); CHUNK_MID(6); CHUNK_LAST(7);

    // row denominators: lanes {l, l^16, l^32, l^48} share row m15
    lsum += __shfl_xor(lsum, 16, 64);
    lsum += __shfl_xor(lsum, 32, 64);

    const float rinv0 = 1.f / __shfl(lsum, q * 4 + 0, 64);
    const float rinv1 = 1.f / __shfl(lsum, q * 4 + 1, 64);
    const float rinv2 = 1.f / __shfl(lsum, q * 4 + 2, 64);
    const float rinv3 = 1.f / __shfl(lsum, q * 4 + 3, 64);

    EPI(0, acc0); EPI(1, acc1); EPI(2, acc2); EPI(3, acc3);
}

// ------------------------------------------------------------------
extern "C" void kernel_launch(void* const* d_in, const int* in_sizes, int n_in,
                              void* d_out, int out_size, void* d_ws, size_t ws_size,
                              hipStream_t stream)
{
    const float* x    = (const float*)d_in[0];
    const int*   adj  = (const int*)  d_in[1];
    const float* emb1 = (const float*)d_in[2];
    const float* emb2 = (const float*)d_in[3];
    const float* W    = (const float*)d_in[4];
    const float* a    = (const float*)d_in[5];
    const float* a2   = (const float*)d_in[6];
    float* out = (float*)d_out;

    unsigned short* WhSw = (unsigned short*)d_ws;             // 6.29 MB
    float* s1 = (float*)(WhSw + (size_t)BT * 65536);
    float* s2 = s1 + BT * N;
    float* f1 = s2 + BT * N;
    float* f2 = f1 + N;
    unsigned int* adjBits = (unsigned int*)(f2 + N);          // 128 KB

    hipLaunchKernelGGL(k_proj_misc, dim3(768), dim3(256), 0, stream,
                       x, W, a, adj, emb1, emb2, a2, WhSw, s1, s2, adjBits, f1, f2);
    hipLaunchKernelGGL(k_attn, dim3(BT * 16), dim3(256), 0, stream,
                       adjBits, WhSw, s1, s2, f1, f2, out);
}

// Round 14
// 110.656 us; speedup vs baseline: 2.4346x; 1.0525x over previous
//
#include <hip/hip_runtime.h>
#include <hip/hip_bf16.h>
#include <math.h>

#define BT 48
#define N 1024
#define F 64
#define CIN 64
#define EM 16
#define LRELU_A 0.2f
#define L2E 1.4426950408889634f

typedef short bf16x8 __attribute__((ext_vector_type(8)));   // 8 bf16 = 4 VGPRs
typedef float f32x4  __attribute__((ext_vector_type(4)));
typedef float f32x2  __attribute__((ext_vector_type(2)));
typedef float f32x4e __attribute__((ext_vector_type(4)));
typedef unsigned int u32x4 __attribute__((ext_vector_type(4)));

// exact RTNE float->bf16 bits (k_proj only, off hot path)
__device__ __forceinline__ unsigned short f2bf(float f) {
    unsigned int u = __float_as_uint(f);
    return (unsigned short)((u + 0x7FFFu + ((u >> 16) & 1u)) >> 16);
}

// packed fp32 FMA: acc = x*w + acc (two lanes' worth in one inst)
#define PKFMA(acc, xp, wp) \
    asm("v_pk_fma_f32 %0, %1, %2, %0" : "+v"(acc) : "v"(xp), "v"(wp))

// ------------------------------------------------------------------
// k_proj_misc round 21 "regtile": composite-cost cut. Old: 272
// ds_read_b128 + 1024 scalar fmaf per thread (LDS 16us + VALU 10us
// per-CU). New: 16x16 thread grid, thread owns 4 rows x 4 cols.
// x staged TRANSPOSED with XOR row-swizzle (stride 72; s and r0 both
// live in bits 2-5, j in bits 0-1 -> (r0+j)^s == (r0^s)+j, so b128
// reads stay contiguous+aligned). Per k: 2 ds_read_b128 + 8 pk_fma
// (= 16 FMA) -> LDS -53%, FMA issue -50%. Accumulation k-ascending
// per output => Wh/WhSw BIT-IDENTICAL to round 13. s1/s2 reduction
// order changes (thread-local 4-col dot + 16-lane butterfly) — fp32
// noise ~1e-6, far under tolerance.
// ------------------------------------------------------------------
__global__ __launch_bounds__(256) void k_proj_misc(
    const float* __restrict__ x, const float* __restrict__ W,
    const float* __restrict__ a,
    const int* __restrict__ adj,
    const float* __restrict__ emb1, const float* __restrict__ emb2,
    const float* __restrict__ a2,
    unsigned short* __restrict__ WhSw,
    float* __restrict__ s1, float* __restrict__ s2,
    unsigned int* __restrict__ adjBits,
    float* __restrict__ f1, float* __restrict__ f2)
{
    const int tid = threadIdx.x;
    const int b   = blockIdx.x;

    __shared__ __align__(16) float sxT[64 * 72];            // x^T, row-swizzled
    __shared__ __align__(16) float sW[64 * 68];             // W [k][c]
    __shared__ __align__(16) unsigned short sT[64 * 80];    // bf16 Wh staging

    const int bt  = b >> 4;
    const int n0  = (b & 15) * 64;
    const size_t grow = (size_t)bt * N + n0;

    {
        const float4* xv = (const float4*)(x + grow * CIN);
        for (int i = tid; i < 1024; i += 256) {
            const float4 v = xv[i];
            const int row = i >> 4, c4 = (i & 15) * 4;
            sxT[(c4 + 0) * 72 + (row ^ (((c4 + 0) & 15) << 2))] = v.x;
            sxT[(c4 + 1) * 72 + (row ^ (((c4 + 1) & 15) << 2))] = v.y;
            sxT[(c4 + 2) * 72 + (row ^ (((c4 + 2) & 15) << 2))] = v.z;
            sxT[(c4 + 3) * 72 + (row ^ (((c4 + 3) & 15) << 2))] = v.w;
        }
        const float4* wv = (const float4*)W;
        for (int i = tid; i < 1024; i += 256) {
            const int k = i >> 4, c4 = (i & 15) * 4;
            *(float4*)&sW[k * 68 + c4] = wv[i];
        }
    }
    __syncthreads();

    const int rg = tid >> 4, cg = tid & 15;
    const int r0 = rg * 4, c0 = cg * 4;

    f32x2 a00 = 0.f, a01 = 0.f, a10 = 0.f, a11 = 0.f;
    f32x2 a20 = 0.f, a21 = 0.f, a30 = 0.f, a31 = 0.f;

#pragma unroll
    for (int k = 0; k < CIN; ++k) {
        const float4 xr  = *(const float4*)&sxT[k * 72 + (r0 ^ ((k & 15) << 2))];
        const float4 wv4 = *(const float4*)&sW[k * 68 + c0];
        f32x2 w01; w01.x = wv4.x; w01.y = wv4.y;
        f32x2 w23; w23.x = wv4.z; w23.y = wv4.w;
        f32x2 xb;
        xb.x = xr.x; xb.y = xr.x;
        PKFMA(a00, xb, w01); PKFMA(a01, xb, w23);
        xb.x = xr.y; xb.y = xr.y;
        PKFMA(a10, xb, w01); PKFMA(a11, xb, w23);
        xb.x = xr.z; xb.y = xr.z;
        PKFMA(a20, xb, w01); PKFMA(a21, xb, w23);
        xb.x = xr.w; xb.y = xr.w;
        PKFMA(a30, xb, w01); PKFMA(a31, xb, w23);
    }

    // s1/s2: thread-local 4-col dot, then butterfly over the 16 cg lanes
    {
        const float4 aw1 = *(const float4*)&a[c0];
        const float4 aw2 = *(const float4*)&a[F + c0];
        float v1r0 = a00.x*aw1.x + a00.y*aw1.y + a01.x*aw1.z + a01.y*aw1.w;
        float v1r1 = a10.x*aw1.x + a10.y*aw1.y + a11.x*aw1.z + a11.y*aw1.w;
        float v1r2 = a20.x*aw1.x + a20.y*aw1.y + a21.x*aw1.z + a21.y*aw1.w;
        float v1r3 = a30.x*aw1.x + a30.y*aw1.y + a31.x*aw1.z + a31.y*aw1.w;
        float v2r0 = a00.x*aw2.x + a00.y*aw2.y + a01.x*aw2.z + a01.y*aw2.w;
        float v2r1 = a10.x*aw2.x + a10.y*aw2.y + a11.x*aw2.z + a11.y*aw2.w;
        float v2r2 = a20.x*aw2.x + a20.y*aw2.y + a21.x*aw2.z + a21.y*aw2.w;
        float v2r3 = a30.x*aw2.x + a30.y*aw2.y + a31.x*aw2.z + a31.y*aw2.w;
#pragma unroll
        for (int off = 1; off <= 8; off <<= 1) {
            v1r0 += __shfl_xor(v1r0, off, 64); v2r0 += __shfl_xor(v2r0, off, 64);
            v1r1 += __shfl_xor(v1r1, off, 64); v2r1 += __shfl_xor(v2r1, off, 64);
            v1r2 += __shfl_xor(v1r2, off, 64); v2r2 += __shfl_xor(v2r2, off, 64);
            v1r3 += __shfl_xor(v1r3, off, 64); v2r3 += __shfl_xor(v2r3, off, 64);
        }
        if (cg == 0) {
            s1[grow + r0 + 0] = v1r0; s2[grow + r0 + 0] = v2r0;
            s1[grow + r0 + 1] = v1r1; s2[grow + r0 + 1] = v2r1;
            s1[grow + r0 + 2] = v1r2; s2[grow + r0 + 2] = v2r2;
            s1[grow + r0 + 3] = v1r3; s2[grow + r0 + 3] = v2r3;
        }
    }

    // bf16 Wh -> sT[f][row]  (same semantic as old sT)
    sT[(c0+0)*80 + r0+0] = f2bf(a00.x); sT[(c0+1)*80 + r0+0] = f2bf(a00.y);
    sT[(c0+2)*80 + r0+0] = f2bf(a01.x); sT[(c0+3)*80 + r0+0] = f2bf(a01.y);
    sT[(c0+0)*80 + r0+1] = f2bf(a10.x); sT[(c0+1)*80 + r0+1] = f2bf(a10.y);
    sT[(c0+2)*80 + r0+1] = f2bf(a11.x); sT[(c0+3)*80 + r0+1] = f2bf(a11.y);
    sT[(c0+0)*80 + r0+2] = f2bf(a20.x); sT[(c0+1)*80 + r0+2] = f2bf(a20.y);
    sT[(c0+2)*80 + r0+2] = f2bf(a21.x); sT[(c0+3)*80 + r0+2] = f2bf(a21.y);
    sT[(c0+0)*80 + r0+3] = f2bf(a30.x); sT[(c0+1)*80 + r0+3] = f2bf(a30.y);
    sT[(c0+2)*80 + r0+3] = f2bf(a31.x); sT[(c0+3)*80 + r0+3] = f2bf(a31.y);
    __syncthreads();

    {
        const int ff = tid >> 2, qq = tid & 3;
        const int slot = (qq + ff) & 3;
        const int nb0 = (b & 15) * 2;
#pragma unroll
        for (int nbL = 0; nbL < 2; ++nbL) {
            const size_t dst = ((size_t)(bt * 32 + nb0 + nbL) * 64 + ff) * 32 + slot * 8;
            *(uint4*)&WhSw[dst] = *(const uint4*)&sT[ff * 80 + nbL * 32 + qq * 8];
        }
    }

    if (b < 128) {
        const int idx = b * 256 + tid;
        const int r = idx >> 5, w32 = idx & 31;
        const int* p = adj + (size_t)r * N + w32 * 32;
        unsigned int m = 0;
#pragma unroll
        for (int j = 0; j < 32; ++j) m |= (p[j] > 0 ? 1u : 0u) << j;
        adjBits[idx] = m;
    } else if (b < 132) {
        const int n = (b - 128) * 256 + tid;
        float v1 = 0.f, v2 = 0.f;
#pragma unroll
        for (int k = 0; k < EM; ++k) {
            v1 = fmaf(emb1[n * EM + k], a2[k], v1);
            v2 = fmaf(emb2[n * EM + k], a2[EM + k], v2);
        }
        f1[n] = v1; f2[n] = v2;
    }
}

// ------------------------------------------------------------------
// k_attn round 21: R13 regB-pp structure, PAIR -> packed fp32 mul
// (v_pk_mul_f32 on float4 subpairs via shufflevector, zero-cost
// subreg). 9 inst / 2 elems vs 11. Products bit-identical.
// ------------------------------------------------------------------

#define PAIRPK(x1p, x2p, bit, dest) do {                                   \
    f32x2 m1_, m2_;                                                        \
    asm("v_pk_mul_f32 %0, %1, %2" : "=v"(m1_) : "v"(x1p), "v"(E1p));       \
    asm("v_pk_mul_f32 %0, %1, %2" : "=v"(m2_) : "v"(x2p), "v"(E2p));       \
    float p0_ = fmaxf(m1_.x, m2_.x);                                       \
    float p1_ = fmaxf(m1_.y, m2_.y);                                       \
    p0_ = ((mb_ >> (bit)) & 1u) ? p0_ : 0.f;                               \
    p1_ = ((mb_ >> ((bit) + 1)) & 1u) ? p1_ : 0.f;                         \
    lsum += p0_ + p1_;                                                     \
    unsigned int pk_;                                                      \
    asm("v_cvt_pk_bf16_f32 %0, %1, %2" : "=v"(pk_) : "v"(p0_), "v"(p1_)); \
    dest = pk_;                                                            \
} while (0)

#define MAKE_ONE(ch, ks, Avar, abword) do {                                \
    const int jb_ = (ch) * 128 + (ks) * 32 + q * 8;                        \
    const f32x4e x1a_ = *(const f32x4e*)&sX1[jb_];                         \
    const f32x4e x1b_ = *(const f32x4e*)&sX1[jb_ + 4];                     \
    const f32x4e x2a_ = *(const f32x4e*)&sX2[jb_];                         \
    const f32x4e x2b_ = *(const f32x4e*)&sX2[jb_ + 4];                     \
    const unsigned int mb_ = ((abword) >> (q * 8)) & 0xFFu;                \
    unsigned int u0_, u1_, u2_, u3_;                                       \
    PAIRPK(__builtin_shufflevector(x1a_, x1a_, 0, 1),                      \
           __builtin_shufflevector(x2a_, x2a_, 0, 1), 0, u0_);             \
    PAIRPK(__builtin_shufflevector(x1a_, x1a_, 2, 3),                      \
           __builtin_shufflevector(x2a_, x2a_, 2, 3), 2, u1_);             \
    PAIRPK(__builtin_shufflevector(x1b_, x1b_, 0, 1),                      \
           __builtin_shufflevector(x2b_, x2b_, 0, 1), 4, u2_);             \
    PAIRPK(__builtin_shufflevector(x1b_, x1b_, 2, 3),                      \
           __builtin_shufflevector(x2b_, x2b_, 2, 3), 6, u3_);             \
    u32x4 av_; av_.x = u0_; av_.y = u1_; av_.z = u2_; av_.w = u3_;         \
    Avar = __builtin_bit_cast(bf16x8, av_);                                \
} while (0)

#define MAKE_AFR(ch, abv, A0, A1, A2, A3) do {                             \
    MAKE_ONE(ch, 0, A0, abv.x);                                            \
    MAKE_ONE(ch, 1, A1, abv.y);                                            \
    MAKE_ONE(ch, 2, A2, abv.z);                                            \
    MAKE_ONE(ch, 3, A3, abv.w);                                            \
} while (0)

#define LB(v, ch, ks, ct)                                                  \
    v = *(const bf16x8*)(gBc + (size_t)(ch) * 16384 + (ks) * 4096 +        \
        ((ct) * 16 + m15) * 64 + slotoff)

#define LOAD8(B0, B1, B2, B3, B4, B5, B6, B7, ch, ct0, ct1) do {           \
    LB(B0, ch, 0, ct0); LB(B1, ch, 1, ct0);                                \
    LB(B2, ch, 2, ct0); LB(B3, ch, 3, ct0);                                \
    LB(B4, ch, 0, ct1); LB(B5, ch, 1, ct1);                                \
    LB(B6, ch, 2, ct1); LB(B7, ch, 3, ct1);                                \
} while (0)

#define MFMA8(B0, B1, B2, B3, B4, B5, B6, B7, c0, c1) do {                 \
    acc##c0 = __builtin_amdgcn_mfma_f32_16x16x32_bf16(fA0, B0, acc##c0, 0, 0, 0); \
    acc##c0 = __builtin_amdgcn_mfma_f32_16x16x32_bf16(fA1, B1, acc##c0, 0, 0, 0); \
    acc##c0 = __builtin_amdgcn_mfma_f32_16x16x32_bf16(fA2, B2, acc##c0, 0, 0, 0); \
    acc##c0 = __builtin_amdgcn_mfma_f32_16x16x32_bf16(fA3, B3, acc##c0, 0, 0, 0); \
    acc##c1 = __builtin_amdgcn_mfma_f32_16x16x32_bf16(fA0, B4, acc##c1, 0, 0, 0); \
    acc##c1 = __builtin_amdgcn_mfma_f32_16x16x32_bf16(fA1, B5, acc##c1, 0, 0, 0); \
    acc##c1 = __builtin_amdgcn_mfma_f32_16x16x32_bf16(fA2, B6, acc##c1, 0, 0, 0); \
    acc##c1 = __builtin_amdgcn_mfma_f32_16x16x32_bf16(fA3, B7, acc##c1, 0, 0, 0); \
} while (0)

#define CHUNK_MID(ch) do {                                                 \
    LOAD8(Q0, Q1, Q2, Q3, Q4, Q5, Q6, Q7, ch, 2, 3);                       \
    const uint4 abv_ = abRow4[ch];                                         \
    MAKE_AFR(ch, abv_, fA0, fA1, fA2, fA3);                                \
    MFMA8(P0, P1, P2, P3, P4, P5, P6, P7, 0, 1);                           \
    LOAD8(P0, P1, P2, P3, P4, P5, P6, P7, (ch) + 1, 0, 1);                 \
    MFMA8(Q0, Q1, Q2, Q3, Q4, Q5, Q6, Q7, 2, 3);                           \
} while (0)

#define CHUNK_LAST(ch) do {                                                \
    LOAD8(Q0, Q1, Q2, Q3, Q4, Q5, Q6, Q7, ch, 2, 3);                       \
    const uint4 abv_ = abRow4[ch];                                         \
    MAKE_AFR(ch, abv_, fA0, fA1, fA2, fA3);                                \
    MFMA8(P0, P1, P2, P3, P4, P5, P6, P7, 0, 1);                           \
    MFMA8(Q0, Q1, Q2, Q3, Q4, Q5, Q6, Q7, 2, 3);                           \
} while (0)

#define EPI(ct, accv) do {                                                 \
    float h0_ = accv.x * rinv0, h1_ = accv.y * rinv1,                      \
          h2_ = accv.z * rinv2, h3_ = accv.w * rinv3;                      \
    h0_ = (h0_ > 0.f) ? h0_ : (__expf(h0_) - 1.f);                         \
    h1_ = (h1_ > 0.f) ? h1_ : (__expf(h1_) - 1.f);                         \
    h2_ = (h2_ > 0.f) ? h2_ : (__expf(h2_) - 1.f);                         \
    h3_ = (h3_ > 0.f) ? h3_ : (__expf(h3_) - 1.f);                         \
    float* op_ = out + (size_t)(bt * N + i0 + w * 16 + q * 4) * F          \
                 + (ct) * 16 + m15;                                        \
    op_[0 * F] = h0_; op_[1 * F] = h1_; op_[2 * F] = h2_; op_[3 * F] = h3_;\
} while (0)

__global__ __launch_bounds__(256, 3) void k_attn(
    const unsigned int* __restrict__ adjBits,
    const unsigned short* __restrict__ WhSw,
    const float* __restrict__ s1, const float* __restrict__ s2,
    const float* __restrict__ f1v, const float* __restrict__ f2v,
    float* __restrict__ out)
{
    __shared__ __align__(16) float sX1[N];                  // 2^c   (scaled domain)
    __shared__ __align__(16) float sX2[N];                  // 2^.2c
    __shared__ float sWmax[4];

    const int tid  = threadIdx.x;
    const int xcd = blockIdx.x & 7;                         // XCD swizzle: 6 bt/XCD
    const int idx = blockIdx.x >> 3;
    const int bt  = xcd * 6 + (idx >> 4);
    const int i0  = (idx & 15) * 64;
    const int lane = tid & 63;
    const int w    = tid >> 6;
    const int q    = lane >> 4;
    const int m15  = lane & 15;

    const int growq = i0 + w * 16 + m15;
    const uint4* abRow4 = (const uint4*)(adjBits + (size_t)growq * 32);
    const float rraw = s1[bt * N + growq] + f1v[growq];

    // stage X1/X2 and track block max of c (scaled by log2e)
    float cmax = -1e30f;
    for (int j = tid; j < N; j += 256) {
        const float c = (s2[bt * N + j] + f2v[j]) * L2E;
        sX1[j] = exp2f(c);
        sX2[j] = exp2f(LRELU_A * c);
        cmax = fmaxf(cmax, c);
    }
#pragma unroll
    for (int off = 32; off >= 1; off >>= 1) cmax = fmaxf(cmax, __shfl_xor(cmax, off, 64));
    if (lane == 0) sWmax[w] = cmax;
    __syncthreads();
    const float mx = fmaxf(fmaxf(sWmax[0], sWmax[1]), fmaxf(sWmax[2], sWmax[3]));

    const float r    = rraw * L2E;                          // scaled domain
    const float smx  = r + mx;
    const float mhat = fmaxf(smx, LRELU_A * smx);           // >= every scaled e in row
    const float E1 = exp2f(r - mhat);
    const float E2 = exp2f(LRELU_A * r - mhat);
    f32x2 E1p; E1p.x = E1; E1p.y = E1;
    f32x2 E2p; E2p.x = E2; E2p.y = E2;
    float lsum = 0.f;

    const char* gBc = (const char*)(WhSw + (size_t)bt * 65536);
    const int slotoff = ((q + m15) & 3) * 16;               // XOR-swizzled slot

    f32x4 acc0 = 0.f, acc1 = 0.f, acc2 = 0.f, acc3 = 0.f;
    bf16x8 fA0, fA1, fA2, fA3;
    bf16x8 P0, P1, P2, P3, P4, P5, P6, P7;                  // bank P (32 VGPR)
    bf16x8 Q0, Q1, Q2, Q3, Q4, Q5, Q6, Q7;                  // bank Q (32 VGPR)

    LOAD8(P0, P1, P2, P3, P4, P5, P6, P7, 0, 0, 1);

    CHUNK_MID(0); CHUNK_MID(1); CHUNK_MID(2); CHUNK_MID(3);
    CHUNK_MID(4); CHUNK_MID(5); CHUNK_MID(6); CHUNK_LAST(7);

    // row denominators: lanes {l, l^16, l^32, l^48} share row m15
    lsum += __shfl_xor(lsum, 16, 64);
    lsum += __shfl_xor(lsum, 32, 64);

    const float rinv0 = 1.f / __shfl(lsum, q * 4 + 0, 64);
    const float rinv1 = 1.f / __shfl(lsum, q * 4 + 1, 64);
    const float rinv2 = 1.f / __shfl(lsum, q * 4 + 2, 64);
    const float rinv3 = 1.f / __shfl(lsum, q * 4 + 3, 64);

    EPI(0, acc0); EPI(1, acc1); EPI(2, acc2); EPI(3, acc3);
}

// ------------------------------------------------------------------
extern "C" void kernel_launch(void* const* d_in, const int* in_sizes, int n_in,
                              void* d_out, int out_size, void* d_ws, size_t ws_size,
                              hipStream_t stream)
{
    const float* x    = (const float*)d_in[0];
    const int*   adj  = (const int*)  d_in[1];
    const float* emb1 = (const float*)d_in[2];
    const float* emb2 = (const float*)d_in[3];
    const float* W    = (const float*)d_in[4];
    const float* a    = (const float*)d_in[5];
    const float* a2   = (const float*)d_in[6];
    float* out = (float*)d_out;

    unsigned short* WhSw = (unsigned short*)d_ws;             // 6.29 MB
    float* s1 = (float*)(WhSw + (size_t)BT * 65536);
    float* s2 = s1 + BT * N;
    float* f1 = s2 + BT * N;
    float* f2 = f1 + N;
    unsigned int* adjBits = (unsigned int*)(f2 + N);          // 128 KB

    hipLaunchKernelGGL(k_proj_misc, dim3(768), dim3(256), 0, stream,
                       x, W, a, adj, emb1, emb2, a2, WhSw, s1, s2, adjBits, f1, f2);
    hipLaunchKernelGGL(k_attn, dim3(BT * 16), dim3(256), 0, stream,
                       adjBits, WhSw, s1, s2, f1, f2, out);
}